// Round 1
// baseline (775.834 us; speedup 1.0000x reference)
//
#include <hip/hip_runtime.h>
#include <math.h>

#define SEQ 16384
#define D   1024
#define NBLK 4096      // 4 waves/block, 2 rows/wave -> 8 rows/block
#define NFIN 32        // last 32 ticket-holders run the finalize phase
#define ROWS_PER_WAVE 2

typedef float floatx4 __attribute__((ext_vector_type(4)));

__device__ __forceinline__ floatx4 nt_load4(const float* p) {
  return __builtin_nontemporal_load((const floatx4*)p);
}

// ---------------------------------------------------------------------------
// Fused kernel: logits + per-block softmax partials + last-arriver finalize.
//
// Dot phase (identical math to the proven 2-kernel version): 4096 blocks x
// 256 thr; each wave computes 2 consecutive rows with 8 independent
// nontemporal dwordx4 loads issued back-to-back. Blocks 0..2047 -> head 0,
// 2048..4095 -> head 1.
//
// Tail: each block release-fences its logits/partial stores, then takes an
// atomicAdd ticket. The last NFIN=32 ticket holders (guaranteed resident:
// their tickets prove >=4064 blocks already finished, and only <=31 blocks
// remain, far below free slots) spin until cnt==NBLK, acquire-fence, then
// redundantly reduce their head's 2048 (m,s) partials (16 KB, L2-hot) and
// normalize one 256-float4 slice of the output. This overlaps the softmax
// reduction with the dot grid's drain and removes one kernel launch.
// ---------------------------------------------------------------------------
__global__ __launch_bounds__(256) void fused_kernel(
    const float* __restrict__ g1, const float* __restrict__ g2,
    const float* __restrict__ wp1, const float* __restrict__ wp2,
    float* __restrict__ logits,
    float* __restrict__ blk_m, float* __restrict__ blk_s,
    unsigned int* __restrict__ cnt,
    float4* __restrict__ out4) {
  const int lane = threadIdx.x & 63;
  const int wid  = threadIdx.x >> 6;                    // 0..3
  const int w    = blockIdx.x * 4 + wid;                // 0..16383
  const int r0   = w * ROWS_PER_WAVE;                   // global row pair
  const bool head1 = (blockIdx.x >= NBLK / 2);
  const float* g  = head1 ? g2 : g1;
  const float* wp = head1 ? wp2 : wp1;
  const int row0  = head1 ? (r0 - SEQ) : r0;

  floatx4 wv[4];
#pragma unroll
  for (int k = 0; k < 4; ++k)
    wv[k] = *((const floatx4*)wp + lane + 64 * k);

  const float* row = g + (size_t)row0 * D;

  // Issue all 8 loads before any FMA (independent, nontemporal).
  floatx4 a0 = nt_load4(row + 4 * (lane));
  floatx4 a1 = nt_load4(row + 4 * (lane + 64));
  floatx4 a2 = nt_load4(row + 4 * (lane + 128));
  floatx4 a3 = nt_load4(row + 4 * (lane + 192));
  floatx4 b0 = nt_load4(row + D + 4 * (lane));
  floatx4 b1 = nt_load4(row + D + 4 * (lane + 64));
  floatx4 b2 = nt_load4(row + D + 4 * (lane + 128));
  floatx4 b3 = nt_load4(row + D + 4 * (lane + 192));

  float acc0 = 0.f, acc1 = 0.f;
#pragma unroll
  for (int e = 0; e < 4; ++e) {
    acc0 = fmaf(a0[e], wv[0][e], acc0);
    acc0 = fmaf(a1[e], wv[1][e], acc0);
    acc0 = fmaf(a2[e], wv[2][e], acc0);
    acc0 = fmaf(a3[e], wv[3][e], acc0);
    acc1 = fmaf(b0[e], wv[0][e], acc1);
    acc1 = fmaf(b1[e], wv[1][e], acc1);
    acc1 = fmaf(b2[e], wv[2][e], acc1);
    acc1 = fmaf(b3[e], wv[3][e], acc1);
  }

#pragma unroll
  for (int off = 32; off > 0; off >>= 1) {
    acc0 += __shfl_xor(acc0, off, 64);
    acc1 += __shfl_xor(acc1, off, 64);
  }
  if (lane == 0) {
    *(float2*)(logits + r0) = make_float2(acc0, acc1);
  }

  // per-wave softmax partial
  float mw = fmaxf(acc0, acc1);
  float sw = __expf(acc0 - mw) + __expf(acc1 - mw);

  __shared__ float lm[4], ls[4];
  __shared__ unsigned int ticket_sh;
  if (lane == 0) { lm[wid] = mw; ls[wid] = sw; }
  __syncthreads();
  if (threadIdx.x == 0) {
    float M = fmaxf(fmaxf(lm[0], lm[1]), fmaxf(lm[2], lm[3]));
    float S = ls[0] * __expf(lm[0] - M) + ls[1] * __expf(lm[1] - M) +
              ls[2] * __expf(lm[2] - M) + ls[3] * __expf(lm[3] - M);
    blk_m[blockIdx.x] = M;
    blk_s[blockIdx.x] = S;
  }
  // Release: each storing thread (lane0 of each wave stored logits; thread 0
  // stored the partials) fences its OWN prior global stores device-wide
  // before this block's ticket can be observed.
  if (lane == 0) __threadfence();
  __syncthreads();  // all fences complete before the ticket is taken
  if (threadIdx.x == 0) ticket_sh = atomicAdd(cnt, 1u);
  __syncthreads();
  const unsigned int t = ticket_sh;  // uniform across the block
  if (t < NBLK - NFIN) return;

  // ---------------- finalize phase (last NFIN ticket holders) ----------------
  const int f    = (int)t - (NBLK - NFIN);  // 0..31, unique
  const int head = f >> 4;                  // 16 finalizers per head
  const int tid  = threadIdx.x;

  if (tid == 0) {
    while (__hip_atomic_load(cnt, __ATOMIC_RELAXED, __HIP_MEMORY_SCOPE_AGENT)
           < NBLK)
      __builtin_amdgcn_s_sleep(2);
  }
  __syncthreads();
  __threadfence();  // acquire: invalidate stale cache before reading others' data

  // --- reduce this head's 2048 partials: 8 per thread ---
  const float* pm = blk_m + head * (NBLK / 2) + tid * 8;
  const float* ps = blk_s + head * (NBLK / 2) + tid * 8;
  float M = -INFINITY, S = 0.f;
#pragma unroll
  for (int i = 0; i < 8; ++i) {
    float m = pm[i], s = ps[i];
    float nm = fmaxf(M, m);
    S = S * __expf(M - nm) + s * __expf(m - nm);
    M = nm;
  }
#pragma unroll
  for (int off = 32; off > 0; off >>= 1) {
    float m2 = __shfl_xor(M, off, 64);
    float s2 = __shfl_xor(S, off, 64);
    float nm = fmaxf(M, m2);
    S = S * __expf(M - nm) + s2 * __expf(m2 - nm);
    M = nm;
  }
  __shared__ float sm[4], ss[4], fin[2];
  if (lane == 0) { sm[wid] = M; ss[wid] = S; }
  __syncthreads();
  if (tid == 0) {
    float Mg = -INFINITY, Sg = 0.f;
#pragma unroll
    for (int i = 0; i < 4; ++i) {
      float nm = fmaxf(Mg, sm[i]);
      Sg = Sg * __expf(Mg - nm) + ss[i] * __expf(sm[i] - nm);
      Mg = nm;
    }
    fin[0] = Mg;
    fin[1] = 1.0f / Sg;
  }
  __syncthreads();
  const float Mg   = fin[0];
  const float invS = fin[1];

  // --- normalize this finalizer's slice: 256 float4 ---
  const float4* logits4 = (const float4*)logits;
  const int i = head * 4096 + (f & 15) * 256 + tid;
  float4 v = logits4[i];
  float4 o;
  o.x = __expf(v.x - Mg) * invS;
  o.y = __expf(v.y - Mg) * invS;
  o.z = __expf(v.z - Mg) * invS;
  o.w = __expf(v.w - Mg) * invS;
  out4[i] = o;
}

extern "C" void kernel_launch(void* const* d_in, const int* in_sizes, int n_in,
                              void* d_out, int out_size, void* d_ws, size_t ws_size,
                              hipStream_t stream) {
  const float* g1  = (const float*)d_in[0];
  const float* g2  = (const float*)d_in[1];
  const float* wp1 = (const float*)d_in[2];
  const float* wp2 = (const float*)d_in[3];
  float* out = (float*)d_out;

  float* logits = (float*)d_ws;              // 32768 floats
  float* blk_m  = logits + 2 * SEQ;          // 4096
  float* blk_s  = blk_m + NBLK;              // 4096
  unsigned int* cnt = (unsigned int*)(blk_s + NBLK);  // 1 uint, must be zeroed
                                             // (workspace is poisoned each iter)

  hipMemsetAsync(cnt, 0, sizeof(unsigned int), stream);
  fused_kernel<<<NBLK, 256, 0, stream>>>(g1, g2, wp1, wp2, logits,
                                         blk_m, blk_s, cnt, (float4*)out);
}

// Round 2
// 140.189 us; speedup vs baseline: 5.5342x; 5.5342x over previous
//
#include <hip/hip_runtime.h>
#include <hip/hip_bf16.h>
#include <math.h>

#define SEQ 16384
#define D   1024
#define NBLK_DOT 4096   // 4 waves/block, 2 rows/wave -> 8 rows/block
#define ROWS_PER_WAVE 2

typedef float floatx4 __attribute__((ext_vector_type(4)));

__device__ __forceinline__ floatx4 nt_load4(const float* p) {
  return __builtin_nontemporal_load((const floatx4*)p);
}

// ---------------------------------------------------------------------------
// Kernel 1: logits + per-block softmax partials.
// 4096 blocks x 256 thr = 16384 waves = 2 resident generations (block
// turnover keeps load issue flowing while earlier waves drain).
// Each wave: 2 consecutive rows, 8 independent dwordx4 nontemporal loads
// issued together. Blocks 0..2047 -> head 0, 2048..4095 -> head 1.
//
// NOTE (R1 lesson): do NOT fuse finalize into this kernel. Cross-workgroup
// release/acquire on gfx950 costs buffer_wbl2/buffer_inv (whole per-XCD L2
// flushes) per fence -> 5.5x regression. The dispatch boundary provides the
// same ordering for free.
// ---------------------------------------------------------------------------
__global__ void dot_partial_kernel(
    const float* __restrict__ g1, const float* __restrict__ g2,
    const float* __restrict__ wp1, const float* __restrict__ wp2,
    float* __restrict__ logits,
    float* __restrict__ blk_m, float* __restrict__ blk_s) {
  const int lane = threadIdx.x & 63;
  const int wid  = threadIdx.x >> 6;                    // 0..3
  const int w    = blockIdx.x * 4 + wid;                // 0..16383
  const int r0   = w * ROWS_PER_WAVE;                   // global row pair
  const bool head1 = (blockIdx.x >= NBLK_DOT / 2);
  const float* g  = head1 ? g2 : g1;
  const float* wp = head1 ? wp2 : wp1;
  const int row0  = head1 ? (r0 - SEQ) : r0;

  floatx4 wv[4];
#pragma unroll
  for (int k = 0; k < 4; ++k)
    wv[k] = *((const floatx4*)wp + lane + 64 * k);

  const float* row = g + (size_t)row0 * D;

  // Issue all 8 loads before any FMA (independent, nontemporal).
  floatx4 a0 = nt_load4(row + 4 * (lane));
  floatx4 a1 = nt_load4(row + 4 * (lane + 64));
  floatx4 a2 = nt_load4(row + 4 * (lane + 128));
  floatx4 a3 = nt_load4(row + 4 * (lane + 192));
  floatx4 b0 = nt_load4(row + D + 4 * (lane));
  floatx4 b1 = nt_load4(row + D + 4 * (lane + 64));
  floatx4 b2 = nt_load4(row + D + 4 * (lane + 128));
  floatx4 b3 = nt_load4(row + D + 4 * (lane + 192));

  float acc0 = 0.f, acc1 = 0.f;
#pragma unroll
  for (int e = 0; e < 4; ++e) {
    acc0 = fmaf(a0[e], wv[0][e], acc0);
    acc0 = fmaf(a1[e], wv[1][e], acc0);
    acc0 = fmaf(a2[e], wv[2][e], acc0);
    acc0 = fmaf(a3[e], wv[3][e], acc0);
    acc1 = fmaf(b0[e], wv[0][e], acc1);
    acc1 = fmaf(b1[e], wv[1][e], acc1);
    acc1 = fmaf(b2[e], wv[2][e], acc1);
    acc1 = fmaf(b3[e], wv[3][e], acc1);
  }

#pragma unroll
  for (int off = 32; off > 0; off >>= 1) {
    acc0 += __shfl_xor(acc0, off, 64);
    acc1 += __shfl_xor(acc1, off, 64);
  }
  if (lane == 0) {
    *(float2*)(logits + r0) = make_float2(acc0, acc1);
  }

  // per-wave softmax partial
  float mw = fmaxf(acc0, acc1);
  float sw = __expf(acc0 - mw) + __expf(acc1 - mw);

  __shared__ float lm[4], ls[4];
  if (lane == 0) { lm[wid] = mw; ls[wid] = sw; }
  __syncthreads();
  if (threadIdx.x == 0) {
    float M = fmaxf(fmaxf(lm[0], lm[1]), fmaxf(lm[2], lm[3]));
    float S = ls[0] * __expf(lm[0] - M) + ls[1] * __expf(lm[1] - M) +
              ls[2] * __expf(lm[2] - M) + ls[3] * __expf(lm[3] - M);
    blk_m[blockIdx.x] = M;
    blk_s[blockIdx.x] = S;
  }
}

// ---------------------------------------------------------------------------
// Kernel 2: fused stats + normalize. 32 blocks x 256 threads.
// Blocks 0..15 -> head 0, 16..31 -> head 1. Each block redundantly reduces
// its head's 2048 (m,s) partials (16 KB, L2/L3-hot), then normalizes its
// 256-float4 slice of the output.
// ---------------------------------------------------------------------------
__global__ __launch_bounds__(256) void finalize_kernel(
    const float* __restrict__ blk_m, const float* __restrict__ blk_s,
    const float4* __restrict__ logits4, float4* __restrict__ out4) {
  const int head = blockIdx.x >> 4;          // 16 blocks per head
  const int tid  = threadIdx.x;
  const int lane = tid & 63;
  const int wid  = tid >> 6;

  // --- reduce 2048 partials: 8 per thread ---
  const float* pm = blk_m + head * (NBLK_DOT / 2) + tid * 8;
  const float* ps = blk_s + head * (NBLK_DOT / 2) + tid * 8;
  float M = -INFINITY, S = 0.f;
#pragma unroll
  for (int i = 0; i < 8; ++i) {
    float m = pm[i], s = ps[i];
    float nm = fmaxf(M, m);
    S = S * __expf(M - nm) + s * __expf(m - nm);
    M = nm;
  }
#pragma unroll
  for (int off = 32; off > 0; off >>= 1) {
    float m2 = __shfl_xor(M, off, 64);
    float s2 = __shfl_xor(S, off, 64);
    float nm = fmaxf(M, m2);
    S = S * __expf(M - nm) + s2 * __expf(m2 - nm);
    M = nm;
  }
  __shared__ float sm[4], ss[4], fin[2];
  if (lane == 0) { sm[wid] = M; ss[wid] = S; }
  __syncthreads();
  if (tid == 0) {
    float Mg = -INFINITY, Sg = 0.f;
#pragma unroll
    for (int i = 0; i < 4; ++i) {
      float nm = fmaxf(Mg, sm[i]);
      Sg = Sg * __expf(Mg - nm) + ss[i] * __expf(sm[i] - nm);
      Mg = nm;
    }
    fin[0] = Mg;
    fin[1] = 1.0f / Sg;
  }
  __syncthreads();
  const float Mg   = fin[0];
  const float invS = fin[1];

  // --- normalize this block's slice: 256 float4 ---
  const int i = head * 4096 + (blockIdx.x & 15) * 256 + tid;
  float4 v = logits4[i];
  float4 o;
  o.x = __expf(v.x - Mg) * invS;
  o.y = __expf(v.y - Mg) * invS;
  o.z = __expf(v.z - Mg) * invS;
  o.w = __expf(v.w - Mg) * invS;
  out4[i] = o;
}

extern "C" void kernel_launch(void* const* d_in, const int* in_sizes, int n_in,
                              void* d_out, int out_size, void* d_ws, size_t ws_size,
                              hipStream_t stream) {
  const float* g1  = (const float*)d_in[0];
  const float* g2  = (const float*)d_in[1];
  const float* wp1 = (const float*)d_in[2];
  const float* wp2 = (const float*)d_in[3];
  float* out = (float*)d_out;

  float* logits = (float*)d_ws;              // 32768 floats
  float* blk_m  = logits + 2 * SEQ;          // 4096
  float* blk_s  = blk_m + NBLK_DOT;          // 4096

  dot_partial_kernel<<<NBLK_DOT, 256, 0, stream>>>(g1, g2, wp1, wp2,
                                                   logits, blk_m, blk_s);
  finalize_kernel<<<32, 256, 0, stream>>>(blk_m, blk_s,
                                          (const float4*)logits, (float4*)out);
}